// Round 1
// baseline (180.713 us; speedup 1.0000x reference)
//
#include <hip/hip_runtime.h>
#include <cmath>

// Problem constants (fixed by the reference).
constexpr int B  = 4096;
constexpr int D  = 768;
constexpr int P  = 96;
constexpr int C  = 256;
constexpr int SD = 8;    // D / P

constexpr int TPB  = 256;   // 4 waves per block
constexpr int WPB  = 4;     // waves per block (centroid split)
constexpr int CPW  = C / WPB;  // 64 centroids per wave
constexpr int ROWS = 4;     // rows per thread (amortizes centroid broadcasts)

// ---- numpy fp32 emulation helpers (exact path only, validated absmax=0) ----
__device__ __forceinline__ float tree8(float q0, float q1, float q2, float q3,
                                       float q4, float q5, float q6, float q7)
{
#pragma clang fp contract(off)
    return ((q0 + q1) + (q2 + q3)) + ((q4 + q5) + (q6 + q7));
}

__device__ __forceinline__ float proba_np(const float* __restrict__ cbf,
                                          const float* __restrict__ csq,
                                          int c, float4 va, float4 vb, float vsq)
{
#pragma clang fp contract(off)
    float4 ca = ((const float4*)cbf)[2 * c];
    float4 cb = ((const float4*)cbf)[2 * c + 1];
    float p0 = va.x * ca.x, p1 = va.y * ca.y, p2 = va.z * ca.z, p3 = va.w * ca.w;
    float p4 = vb.x * cb.x, p5 = vb.y * cb.y, p6 = vb.z * cb.z, p7 = vb.w * cb.w;
    float l0 = p0 + p4, l1 = p1 + p5, l2 = p2 + p6, l3 = p3 + p7;
    float vc = (l0 + l2) + (l1 + l3);
    float tt = vsq - 2.0f * vc;
    float u  = tt + csq[c];
    return -u;
}

// Exact numpy-order argmax incl. softmax tie path. Byte-identical semantics to
// the validated kernel (absmax == 0.0). Rare (delta-guard) path only.
__device__ __attribute__((noinline))
int exact_search(const float* __restrict__ cbf, const float* __restrict__ csq,
                 float4 va, float4 vb, float vsq)
{
#pragma clang fp contract(off)
    float best = -3.402823466e38f, second = -3.402823466e38f;
    int bi = 0;
    for (int c = 0; c < C; ++c) {
        float pr = proba_np(cbf, csq, c, va, vb, vsq);
        if (pr > best)        { second = best; best = pr; bi = c; }
        else if (pr > second) { second = pr; }
    }
    int idx = bi;

    if (best - second <= 1.0e-6f) {
        float m = best;
        float r0[8] = {0,0,0,0,0,0,0,0};
        float r1[8] = {0,0,0,0,0,0,0,0};
        for (int cg = 0; cg < 16; ++cg) {
            #pragma unroll
            for (int j = 0; j < 8; ++j) {
                float pr = proba_np(cbf, csq, cg * 8 + j, va, vb, vsq);
                r0[j] += expf(pr - m);
            }
        }
        for (int cg = 16; cg < 32; ++cg) {
            #pragma unroll
            for (int j = 0; j < 8; ++j) {
                float pr = proba_np(cbf, csq, cg * 8 + j, va, vb, vsq);
                r1[j] += expf(pr - m);
            }
        }
        float sum = tree8(r0[0],r0[1],r0[2],r0[3],r0[4],r0[5],r0[6],r0[7])
                  + tree8(r1[0],r1[1],r1[2],r1[3],r1[4],r1[5],r1[6],r1[7]);
        float abest = -1.0f;
        int   ai    = 0;
        for (int c = 0; c < C; ++c) {
            float pr = proba_np(cbf, csq, c, va, vb, vsq);
            float e  = expf(pr - m);
            float a  = e / sum;
            if (a > abest) { abest = a; ai = c; }
        }
        idx = ai;
    }
    return idx;
}

// Broadcast lane `i`'s value to all lanes via v_readlane (uniform index -> SGPR).
// Pure VALU: no LDS/VMEM op, no waitcnt in the hot loop.
__device__ __forceinline__ float rdlane(float x, int i)
{
    return __int_as_float(__builtin_amdgcn_readlane(__float_as_int(x), i));
}

// Block = 4 waves x 64 lanes, covers (partition p) x (256 batch rows).
// Wave w scores centroid range [64w, 64w+64) for all 256 rows (4 rows/thread).
// KEY CHANGE vs previous version: the wave's 64-centroid slab lives in
// REGISTERS, one centroid per lane (lane l of wave w owns centroid t = 64w+l,
// 8 floats + ch = 9 VGPRs). The hot loop broadcasts centroid `ci` with 9
// v_readlane ops instead of 3 LDS reads -> zero memory ops / zero s_waitcnt in
// the loop. FMA chain order, top-2 tracking, wave merge, the 2e-5 guard and
// the exact path are bit-identical to the validated kernel.
__global__ __launch_bounds__(TPB, 6)
void pq_split_kernel(const float* __restrict__ vecs,
                     const float* __restrict__ codebook,
                     float* __restrict__ out)
{
    __shared__ float  cbf [C * SD];              // 8 KB codebook[p] (epilogue+exact)
    __shared__ float  csqn[C];                   // ||c||^2 numpy order (exact path)
    __shared__ float2 part_bs[WPB][ROWS][64];    // 8 KB (best, second)
    __shared__ int    part_i [WPB][ROWS][64];    // 4 KB argmax per range

    const int p = blockIdx.x;
    const int t = threadIdx.x;
    const int w = t >> 6;          // wave id 0..3
    const int l = t & 63;          // lane id
    const int rowbase = blockIdx.y * (64 * ROWS);

    // ---- per-lane centroid regs: centroid index == t (coalesced 32B/lane) ----
    const float* cg = codebook + ((size_t)p * C + t) * SD;
    float4 cra = ((const float4*)cg)[0];
    float4 crb = ((const float4*)cg)[1];

    // ---- load this thread's ROWS sub-vectors (issued early, overlaps) ----
    float4 va[ROWS], vb[ROWS];
    #pragma unroll
    for (int r = 0; r < ROWS; ++r) {
        const float* vptr = vecs + (size_t)(rowbase + 64 * r + l) * D + (size_t)p * SD;
        va[r] = ((const float4*)vptr)[0];
        vb[r] = ((const float4*)vptr)[1];
    }

    // ---- csq (numpy order, exact same arithmetic as before) + fast seed ----
    float ch;
    {
#pragma clang fp contract(off)
        float q0 = cra.x*cra.x, q1 = cra.y*cra.y, q2 = cra.z*cra.z, q3 = cra.w*cra.w;
        float q4 = crb.x*crb.x, q5 = crb.y*crb.y, q6 = crb.z*crb.z, q7 = crb.w*crb.w;
        float s = tree8(q0,q1,q2,q3,q4,q5,q6,q7);
        csqn[t] = s;
        ch = -0.5f * s;
    }
    // stage codebook[p] into LDS from the already-loaded regs (for epilogue/exact)
    ((float4*)cbf)[2 * t]     = cra;
    ((float4*)cbf)[2 * t + 1] = crb;
    // NOTE: no barrier needed before the hot loop — it touches no shared memory.
    // The single __syncthreads below (before the merge) orders cbf/csqn/part_*.

    // ---- fast scoring over this wave's 64 centroids (branchless top-2) ----
    float best[ROWS], second[ROWS];
    int   bi[ROWS];
    #pragma unroll
    for (int r = 0; r < ROWS; ++r) {
        best[r] = -3.402823466e38f; second[r] = -3.402823466e38f; bi[r] = 0;
    }

    const int c0 = w * CPW;
    #pragma unroll 2
    for (int ci = 0; ci < CPW; ++ci) {
        const int c = c0 + ci;
        // broadcast centroid ci of this wave: lane ci holds centroid c0+ci
        float cax = rdlane(cra.x, ci), cay = rdlane(cra.y, ci);
        float caz = rdlane(cra.z, ci), caw = rdlane(cra.w, ci);
        float cbx = rdlane(crb.x, ci), cby = rdlane(crb.y, ci);
        float cbz = rdlane(crb.z, ci), cbw = rdlane(crb.w, ci);
        float chc = rdlane(ch,    ci);
        #pragma unroll
        for (int r = 0; r < ROWS; ++r) {
            float s = fmaf(va[r].x, cax, chc);
            s = fmaf(va[r].y, cay, s);
            s = fmaf(va[r].z, caz, s);
            s = fmaf(va[r].w, caw, s);
            s = fmaf(vb[r].x, cbx, s);
            s = fmaf(vb[r].y, cby, s);
            s = fmaf(vb[r].z, cbz, s);
            s = fmaf(vb[r].w, cbw, s);
            bool gt = s > best[r];
            second[r] = fmaxf(second[r], fminf(s, best[r]));
            bi[r]     = gt ? c : bi[r];
            best[r]   = fmaxf(s, best[r]);
        }
    }

    // ---- publish partials ----
    #pragma unroll
    for (int r = 0; r < ROWS; ++r) {
        part_bs[w][r][l] = make_float2(best[r], second[r]);
        part_i [w][r][l] = bi[r];
    }
    __syncthreads();

    // ---- merge: thread t resolves row rowbase + t (its own j == w, lane l) ----
    {
        float Bst = -3.402823466e38f, Snd = -3.402823466e38f;
        int   I   = 0;
        #pragma unroll
        for (int ww = 0; ww < WPB; ++ww) {
            float2 bs = part_bs[ww][w][l];
            int    iw = part_i [ww][w][l];
            bool gt = bs.x > Bst;                 // strict, ascending ww:
            Snd = fmaxf(Snd, fminf(bs.x, Bst));   // first (smaller c) wins ties
            Snd = fmaxf(Snd, bs.y);
            I   = gt ? iw : I;
            Bst = fmaxf(Bst, bs.x);
        }

        const int row = rowbase + t;
        int idx = I;
        if (Bst - Snd <= 2.0e-5f) {               // near-tie: exact numpy path
            const float* vptr = vecs + (size_t)row * D + (size_t)p * SD;
            float4 xa = ((const float4*)vptr)[0];
            float4 xb = ((const float4*)vptr)[1];
            float q0 = xa.x*xa.x, q1 = xa.y*xa.y, q2 = xa.z*xa.z, q3 = xa.w*xa.w;
            float q4 = xb.x*xb.x, q5 = xb.y*xb.y, q6 = xb.z*xb.z, q7 = xb.w*xb.w;
            float vsq = tree8(q0,q1,q2,q3,q4,q5,q6,q7);
            idx = exact_search(cbf, csqn, xa, xb, vsq);
        }

        float4 o0 = ((const float4*)cbf)[2 * idx];
        float4 o1 = ((const float4*)cbf)[2 * idx + 1];
        float4* op = (float4*)(out + (size_t)row * D + (size_t)p * SD);
        op[0] = o0;
        op[1] = o1;
    }
}

extern "C" void kernel_launch(void* const* d_in, const int* in_sizes, int n_in,
                              void* d_out, int out_size, void* d_ws, size_t ws_size,
                              hipStream_t stream)
{
    const float* vecs     = (const float*)d_in[0];  // [B, D] fp32
    const float* codebook = (const float*)d_in[1];  // [P, C, SD] fp32
    float*       out      = (float*)d_out;          // [B, D] fp32

    dim3 grid(P, B / (64 * ROWS));   // (96, 16) -> 1536 blocks x 4 waves
    dim3 block(TPB);
    pq_split_kernel<<<grid, block, 0, stream>>>(vecs, codebook, out);
}

// Round 2
// 176.891 us; speedup vs baseline: 1.0216x; 1.0216x over previous
//
#include <hip/hip_runtime.h>
#include <cmath>

// Problem constants (fixed by the reference).
constexpr int B  = 4096;
constexpr int D  = 768;
constexpr int P  = 96;
constexpr int C  = 256;
constexpr int SD = 8;    // D / P

constexpr int TPB  = 256;   // 4 waves per block
constexpr int WPB  = 4;     // waves per block (centroid split)
constexpr int CPW  = C / WPB;  // 64 centroids per wave
constexpr int ROWS = 4;     // rows per thread (amortizes LDS centroid reads)

// ---- numpy fp32 emulation helpers (exact path only, validated absmax=0) ----
__device__ __forceinline__ float tree8(float q0, float q1, float q2, float q3,
                                       float q4, float q5, float q6, float q7)
{
#pragma clang fp contract(off)
    return ((q0 + q1) + (q2 + q3)) + ((q4 + q5) + (q6 + q7));
}

__device__ __forceinline__ float proba_np(const float* __restrict__ cbf,
                                          const float* __restrict__ csq,
                                          int c, float4 va, float4 vb, float vsq)
{
#pragma clang fp contract(off)
    float4 ca = ((const float4*)cbf)[2 * c];
    float4 cb = ((const float4*)cbf)[2 * c + 1];
    float p0 = va.x * ca.x, p1 = va.y * ca.y, p2 = va.z * ca.z, p3 = va.w * ca.w;
    float p4 = vb.x * cb.x, p5 = vb.y * cb.y, p6 = vb.z * cb.z, p7 = vb.w * cb.w;
    float l0 = p0 + p4, l1 = p1 + p5, l2 = p2 + p6, l3 = p3 + p7;
    float vc = (l0 + l2) + (l1 + l3);
    float tt = vsq - 2.0f * vc;
    float u  = tt + csq[c];
    return -u;
}

// Exact numpy-order argmax incl. softmax tie path. Byte-identical arithmetic to
// the validated kernel (absmax == 0.0). Rare (delta-guard) path only.
// INLINED (was noinline): the call ABI forced live-across-call state into
// memory and contributed to the 36-VGPR aggressive-spill allocation. As a cold
// branch-sunk region it no longer perturbs the hot loop's register allocation.
__device__ __forceinline__
int exact_search(const float* __restrict__ cbf, const float* __restrict__ csq,
                 float4 va, float4 vb, float vsq)
{
#pragma clang fp contract(off)
    float best = -3.402823466e38f, second = -3.402823466e38f;
    int bi = 0;
    for (int c = 0; c < C; ++c) {
        float pr = proba_np(cbf, csq, c, va, vb, vsq);
        if (pr > best)        { second = best; best = pr; bi = c; }
        else if (pr > second) { second = pr; }
    }
    int idx = bi;

    if (best - second <= 1.0e-6f) {
        float m = best;
        float r0[8] = {0,0,0,0,0,0,0,0};
        float r1[8] = {0,0,0,0,0,0,0,0};
        for (int cg = 0; cg < 16; ++cg) {
            #pragma unroll
            for (int j = 0; j < 8; ++j) {
                float pr = proba_np(cbf, csq, cg * 8 + j, va, vb, vsq);
                r0[j] += expf(pr - m);
            }
        }
        for (int cg = 16; cg < 32; ++cg) {
            #pragma unroll
            for (int j = 0; j < 8; ++j) {
                float pr = proba_np(cbf, csq, cg * 8 + j, va, vb, vsq);
                r1[j] += expf(pr - m);
            }
        }
        float sum = tree8(r0[0],r0[1],r0[2],r0[3],r0[4],r0[5],r0[6],r0[7])
                  + tree8(r1[0],r1[1],r1[2],r1[3],r1[4],r1[5],r1[6],r1[7]);
        float abest = -1.0f;
        int   ai    = 0;
        for (int c = 0; c < C; ++c) {
            float pr = proba_np(cbf, csq, c, va, vb, vsq);
            float e  = expf(pr - m);
            float a  = e / sum;
            if (a > abest) { abest = a; ai = c; }
        }
        idx = ai;
    }
    return idx;
}

// Block = 4 waves x 64 lanes, covers (partition p) x (256 batch rows).
// Wave w scores centroid range [64w, 64w+64) for all 256 rows (4 rows/thread),
// then per-row top-2 partials are merged across waves through LDS.
//
// KEY CHANGE vs rounds 0/1: __launch_bounds__(256, 4) instead of (256, 6).
// The 6-waves/SIMD promise capped VGPRs at ~85 and (with the noinline call)
// drove the allocator to a 36-VGPR aggressive-spill allocation — per-iteration
// scratch reloads (vmcnt waits) were the 75% stall. Cap 128 regs / 4 waves per
// SIMD lets the ~70 live values stay in registers. Inner loop is the
// LDS-broadcast form (wave-uniform ds_read = conflict-free broadcast, fewer
// instructions than readlane). All arithmetic identical to validated kernel.
__global__ __launch_bounds__(TPB, 4)
void pq_split_kernel(const float* __restrict__ vecs,
                     const float* __restrict__ codebook,
                     float* __restrict__ out)
{
    __shared__ float  cbf [C * SD];              // 8 KB codebook[p]
    __shared__ float  csqn[C];                   // ||c||^2 numpy order (exact path)
    __shared__ float  csqh[C];                   // -0.5*csq (fast seed)
    __shared__ float2 part_bs[WPB][ROWS][64];    // 8 KB (best, second)
    __shared__ int    part_i [WPB][ROWS][64];    // 4 KB argmax per range

    const int p = blockIdx.x;
    const int t = threadIdx.x;
    const int w = t >> 6;          // wave id 0..3
    const int l = t & 63;          // lane id
    const int rowbase = blockIdx.y * (64 * ROWS);

    // ---- per-lane centroid load: centroid index == t (coalesced 32B/lane) ----
    const float* cg = codebook + ((size_t)p * C + t) * SD;
    float4 cra = ((const float4*)cg)[0];
    float4 crb = ((const float4*)cg)[1];

    // ---- load this thread's ROWS sub-vectors (issued early, overlaps) ----
    float4 va[ROWS], vb[ROWS];
    #pragma unroll
    for (int r = 0; r < ROWS; ++r) {
        const float* vptr = vecs + (size_t)(rowbase + 64 * r + l) * D + (size_t)p * SD;
        va[r] = ((const float4*)vptr)[0];
        vb[r] = ((const float4*)vptr)[1];
    }

    // ---- csq from regs (numpy order, same arithmetic as validated) ----
    {
#pragma clang fp contract(off)
        float q0 = cra.x*cra.x, q1 = cra.y*cra.y, q2 = cra.z*cra.z, q3 = cra.w*cra.w;
        float q4 = crb.x*crb.x, q5 = crb.y*crb.y, q6 = crb.z*crb.z, q7 = crb.w*crb.w;
        float s = tree8(q0,q1,q2,q3,q4,q5,q6,q7);
        csqn[t] = s;
        csqh[t] = -0.5f * s;
    }
    // stage codebook[p] into LDS from the already-loaded regs
    ((float4*)cbf)[2 * t]     = cra;
    ((float4*)cbf)[2 * t + 1] = crb;
    __syncthreads();   // cbf/csqh ready for the broadcast loop

    // ---- fast scoring over this wave's 64 centroids (branchless top-2) ----
    float best[ROWS], second[ROWS];
    int   bi[ROWS];
    #pragma unroll
    for (int r = 0; r < ROWS; ++r) {
        best[r] = -3.402823466e38f; second[r] = -3.402823466e38f; bi[r] = 0;
    }

    const int c0 = w * CPW;
    #pragma unroll 4
    for (int ci = 0; ci < CPW; ++ci) {
        const int c = c0 + ci;
        float4 ca = ((const float4*)cbf)[2 * c];     // wave-uniform broadcast
        float4 cb = ((const float4*)cbf)[2 * c + 1];
        float  ch = csqh[c];
        #pragma unroll
        for (int r = 0; r < ROWS; ++r) {
            float s = fmaf(va[r].x, ca.x, ch);
            s = fmaf(va[r].y, ca.y, s);
            s = fmaf(va[r].z, ca.z, s);
            s = fmaf(va[r].w, ca.w, s);
            s = fmaf(vb[r].x, cb.x, s);
            s = fmaf(vb[r].y, cb.y, s);
            s = fmaf(vb[r].z, cb.z, s);
            s = fmaf(vb[r].w, cb.w, s);
            bool gt = s > best[r];
            second[r] = fmaxf(second[r], fminf(s, best[r]));
            bi[r]     = gt ? c : bi[r];
            best[r]   = fmaxf(s, best[r]);
        }
    }

    // ---- publish partials ----
    #pragma unroll
    for (int r = 0; r < ROWS; ++r) {
        part_bs[w][r][l] = make_float2(best[r], second[r]);
        part_i [w][r][l] = bi[r];
    }
    __syncthreads();

    // ---- merge: thread t resolves row rowbase + t (its own j == w, lane l) ----
    {
        float Bst = -3.402823466e38f, Snd = -3.402823466e38f;
        int   I   = 0;
        #pragma unroll
        for (int ww = 0; ww < WPB; ++ww) {
            float2 bs = part_bs[ww][w][l];
            int    iw = part_i [ww][w][l];
            bool gt = bs.x > Bst;                 // strict, ascending ww:
            Snd = fmaxf(Snd, fminf(bs.x, Bst));   // first (smaller c) wins ties
            Snd = fmaxf(Snd, bs.y);
            I   = gt ? iw : I;
            Bst = fmaxf(Bst, bs.x);
        }

        const int row = rowbase + t;
        int idx = I;
        if (Bst - Snd <= 2.0e-5f) {               // near-tie: exact numpy path
            const float* vptr = vecs + (size_t)row * D + (size_t)p * SD;
            float4 xa = ((const float4*)vptr)[0];
            float4 xb = ((const float4*)vptr)[1];
            float q0 = xa.x*xa.x, q1 = xa.y*xa.y, q2 = xa.z*xa.z, q3 = xa.w*xa.w;
            float q4 = xb.x*xb.x, q5 = xb.y*xb.y, q6 = xb.z*xb.z, q7 = xb.w*xb.w;
            float vsq = tree8(q0,q1,q2,q3,q4,q5,q6,q7);
            idx = exact_search(cbf, csqn, xa, xb, vsq);
        }

        float4 o0 = ((const float4*)cbf)[2 * idx];
        float4 o1 = ((const float4*)cbf)[2 * idx + 1];
        float4* op = (float4*)(out + (size_t)row * D + (size_t)p * SD);
        op[0] = o0;
        op[1] = o1;
    }
}

extern "C" void kernel_launch(void* const* d_in, const int* in_sizes, int n_in,
                              void* d_out, int out_size, void* d_ws, size_t ws_size,
                              hipStream_t stream)
{
    const float* vecs     = (const float*)d_in[0];  // [B, D] fp32
    const float* codebook = (const float*)d_in[1];  // [P, C, SD] fp32
    float*       out      = (float*)d_out;          // [B, D] fp32

    dim3 grid(P, B / (64 * ROWS));   // (96, 16) -> 1536 blocks x 4 waves
    dim3 block(TPB);
    pq_split_kernel<<<grid, block, 0, stream>>>(vecs, codebook, out);
}